// Round 9
// baseline (550.076 us; speedup 1.0000x reference)
//
#include <hip/hip_runtime.h>
#include <stdint.h>

#define BB 8
#define CC 16
#define HH 96
#define WW 96
#define HID 128
#define HW (HH*WW)            // 9216
#define CHW (CC*HW)           // 147456
#define NPIX (BB*HW)          // 73728
#define STEPS 16

// ---------------- Threefry-2x32 (JAX-compatible, 20 rounds) ----------------
__host__ __device__ inline void threefry2x32(uint32_t k0, uint32_t k1,
                                             uint32_t x0, uint32_t x1,
                                             uint32_t& o0, uint32_t& o1) {
  const uint32_t ks2 = k0 ^ k1 ^ 0x1BD11BDAu;
  uint32_t v0 = x0 + k0, v1 = x1 + k1;
#define RL(v, r) (((v) << (r)) | ((v) >> (32 - (r))))
#define RND(r) { v0 += v1; v1 = RL(v1, r); v1 ^= v0; }
  RND(13) RND(15) RND(26) RND(6)   v0 += k1;  v1 += ks2 + 1u;
  RND(17) RND(29) RND(16) RND(24)  v0 += ks2; v1 += k0 + 2u;
  RND(13) RND(15) RND(26) RND(6)   v0 += k0;  v1 += k1 + 3u;
  RND(17) RND(29) RND(16) RND(24)  v0 += k1;  v1 += ks2 + 4u;
  RND(13) RND(15) RND(26) RND(6)   v0 += ks2; v1 += k0 + 5u;
#undef RND
#undef RL
  o0 = v0; o1 = v1;
}

// fire: jax.random.uniform(key_i,(B,1,H,W)) < 0.5 ; partitionable threefry:
// bits[j] = x0 ^ x1 of threefry(key_i, (0, j)); u<0.5 <=> top bit clear.
__device__ inline float fire_val(uint32_t ka, uint32_t kb, uint32_t j) {
  uint32_t r0, r1;
  threefry2x32(ka, kb, 0u, j, r0, r1);
  return ((r0 ^ r1) & 0x80000000u) ? 0.0f : 1.0f;
}

// ---------------- w2 transpose: (16,128) -> (128,16) ----------------
__global__ void transp_w2(const float* __restrict__ w2, float* __restrict__ w2t) {
  int i = threadIdx.x + blockIdx.x * blockDim.x;
  if (i < CC * HID) {
    int o = i / HID, k = i - o * HID;
    w2t[k * CC + o] = w2[i];
  }
}

// ---------------- Fused step kernel -----------------------------------------
// Lessons baked in: weights via SCALAR loads only (R8: LDS broadcast weight
// stream = 16 useful B per b128 slot -> ~23us/CU of LDS issue); features
// PINNED in VGPRs via asm (R7: compiler remat of p[] as per-FMA LDS reads);
// 2 pixels/lane so each weight row feeds 128 FMAs (256 cyc) >> s_load latency.
// Block = 256 thr = 4 waves over a 16x8 tile (128 px); lane: px0=lane,
// px1=lane+64; wave q owns 32 of 128 hidden rows. Grid 576 = 8 x 72 tiles.
__global__ __launch_bounds__(256) void ca_fused(
    const float* __restrict__ src,     // x0 (step 0) or raw_{i-1}
    const float* __restrict__ plprev,  // prelife_{i-1} (ignored when step 0)
    const float* __restrict__ w1,  const float* __restrict__ b1,
    const float* __restrict__ w2t, const float* __restrict__ b2,
    float* __restrict__ rawout, float* __restrict__ plout,
    uint32_t ka, uint32_t kb, int apply_life)
{
  __shared__ float xt[CC][180];      // x_i tile 10x18 (pitch 18)  11.52 KiB
  __shared__ float raw3[240];        // raw ch3 12x20
  __shared__ float life_l[180];      // life on 10x18
  __shared__ float fire_lds[128];
  __shared__ float ovl[4 * CC * 128]; // overlay p_lds(24K)/red(32K)
#define P_LDS(f, px) ovl[(f) * 128 + (px)]
#define RED(qq, k, px) ovl[(((qq) * CC) + (k)) * 128 + (px)]

  const int tid  = threadIdx.x;
  const int lane = tid & 63;
  const int q    = __builtin_amdgcn_readfirstlane(tid >> 6);  // wave-uniform
  const int b    = blockIdx.x & 7;           // batch == XCD slot
  const int t    = blockIdx.x >> 3;          // tile 0..71
  const int h0   = (t / 6) * 8, w0 = (t % 6) * 16;

  // ---- A1: raw ch3 12x20 + A2: life on 10x18 (only when applying life)
  if (apply_life) {
    if (tid < 240) {
      const int r = tid / 20, c = tid - r * 20;
      const int hh = h0 - 2 + r, ww = w0 - 2 + c;
      float v = 0.f;
      if (hh >= 0 && hh < HH && ww >= 0 && ww < WW)
        v = src[b * CHW + 3 * HW + hh * WW + ww];
      raw3[tid] = v;
    }
    __syncthreads();
    if (tid < 180) {
      const int r = tid / 18, c = tid - r * 18;
      float m = fmaxf(fmaxf(raw3[r * 20 + c],       raw3[r * 20 + c + 1]),
                      fmaxf(raw3[r * 20 + c + 2],   raw3[(r + 1) * 20 + c]));
      m = fmaxf(m, fmaxf(raw3[(r + 1) * 20 + c + 1], raw3[(r + 1) * 20 + c + 2]));
      m = fmaxf(m, fmaxf(raw3[(r + 2) * 20 + c],     raw3[(r + 2) * 20 + c + 1]));
      m = fmaxf(m, raw3[(r + 2) * 20 + c + 2]);
      const int hh = h0 - 1 + r, ww = w0 - 1 + c;
      float pl = 0.f;
      if (hh >= 0 && hh < HH && ww >= 0 && ww < WW)
        pl = plprev[b * HW + hh * WW + ww];
      life_l[tid] = ((m > 0.1f) && (pl > 0.1f)) ? 1.f : 0.f;
    }
    __syncthreads();
  }

  // ---- A3: build x_i tile (10x18 x 16ch), zero outside image
  for (int i = tid; i < CC * 180; i += 256) {
    const int ch = i / 180, rc = i - ch * 180;
    const int r = rc / 18, c = rc - r * 18;
    const int hh = h0 - 1 + r, ww = w0 - 1 + c;
    float v = 0.f;
    if (hh >= 0 && hh < HH && ww >= 0 && ww < WW) {
      v = src[b * CHW + ch * HW + hh * WW + ww];
      if (apply_life) {
        v *= life_l[rc];
        v = fminf(fmaxf(v, -10.f), 10.f);
      }
    }
    xt[ch][rc] = v;
  }
  __syncthreads();

  // ---- A4: prelife_i (tid<128) + fire (tid>=128) for the 128 interior px
  if (tid < 128) {
    const int py = tid >> 4, pxx = tid & 15;
    const int base = py * 18 + pxx;
    float m = fmaxf(fmaxf(xt[3][base],      xt[3][base + 1]),
                    fmaxf(xt[3][base + 2],  xt[3][base + 18]));
    m = fmaxf(m, fmaxf(xt[3][base + 19], xt[3][base + 20]));
    m = fmaxf(m, fmaxf(xt[3][base + 36], xt[3][base + 37]));
    m = fmaxf(m, xt[3][base + 38]);
    plout[b * HW + (h0 + py) * WW + w0 + pxx] = m;
  } else {
    const int i = tid - 128;
    const int py = i >> 4, pxx = i & 15;
    fire_lds[i] = fire_val(ka, kb, (uint32_t)(b * HW + (h0 + py) * WW + w0 + pxx));
  }

  // ---- B: perception (wave q: channels q,q+4,q+8,q+12; 128 px = 2 iters)
#pragma unroll
  for (int cc = 0; cc < 4; ++cc) {
    const int c = q + cc * 4;            // wave-uniform
    const float* xc = &xt[c][0];
#pragma unroll
    for (int it = 0; it < 2; ++it) {
      const int px = lane + it * 64;
      const int ctr = ((px >> 4) + 1) * 18 + (px & 15) + 1;
      const float v00 = xc[ctr - 19], v01 = xc[ctr - 18], v02 = xc[ctr - 17];
      const float v10 = xc[ctr - 1],  v11 = xc[ctr],      v12 = xc[ctr + 1];
      const float v20 = xc[ctr + 17], v21 = xc[ctr + 18], v22 = xc[ctr + 19];
      P_LDS(c, px)          = v11;
      P_LDS(CC + c, px)     = ((v02 - v00) + 2.f * (v12 - v10) + (v22 - v20)) * 0.125f;
      P_LDS(2 * CC + c, px) = ((v20 - v00) + 2.f * (v21 - v01) + (v22 - v02)) * 0.125f;
    }
  }
  __syncthreads();

  // ---- B2: both pixels' features into registers, PINNED (no remat to LDS)
  float p0[3 * CC], p1[3 * CC];
#pragma unroll
  for (int f = 0; f < 3 * CC; ++f) p0[f] = P_LDS(f, lane);
#pragma unroll
  for (int f = 0; f < 3 * CC; ++f) p1[f] = P_LDS(f, lane + 64);
#pragma unroll
  for (int f = 0; f < 3 * CC; ++f) asm volatile("" : "+v"(p0[f]));
#pragma unroll
  for (int f = 0; f < 3 * CC; ++f) asm volatile("" : "+v"(p1[f]));

  // ---- C: MLP, 32 hidden rows per wave, 2 px per lane, s_load weights
  float upd0[CC], upd1[CC];
#pragma unroll
  for (int k = 0; k < CC; ++k) { upd0[k] = 0.f; upd1[k] = 0.f; }

  const int row0 = q * 32;
#pragma unroll 2
  for (int o = 0; o < 32; ++o) {
    const int row = row0 + o;
    const float4* wr4 = reinterpret_cast<const float4*>(w1 + row * 48);
    const float bb = b1[row];
    float a0 = bb, a1 = 0.f, a2 = 0.f, a3 = 0.f;
    float a4 = bb, a5 = 0.f, a6 = 0.f, a7 = 0.f;
#pragma unroll
    for (int c = 0; c < 12; ++c) {
      const float4 wv = wr4[c];            // wave-uniform -> s_load_dwordx4
      a0 = fmaf(wv.x, p0[4 * c    ], a0);
      a1 = fmaf(wv.y, p0[4 * c + 1], a1);
      a2 = fmaf(wv.z, p0[4 * c + 2], a2);
      a3 = fmaf(wv.w, p0[4 * c + 3], a3);
      a4 = fmaf(wv.x, p1[4 * c    ], a4);
      a5 = fmaf(wv.y, p1[4 * c + 1], a5);
      a6 = fmaf(wv.z, p1[4 * c + 2], a6);
      a7 = fmaf(wv.w, p1[4 * c + 3], a7);
    }
    const float y0 = fmaxf((a0 + a1) + (a2 + a3), 0.f);
    const float y1 = fmaxf((a4 + a5) + (a6 + a7), 0.f);
    const float4* w2r4 = reinterpret_cast<const float4*>(w2t + row * CC);
#pragma unroll
    for (int c = 0; c < 4; ++c) {
      const float4 wv = w2r4[c];           // wave-uniform -> s_load_dwordx4
      upd0[4 * c    ] = fmaf(wv.x, y0, upd0[4 * c    ]);
      upd0[4 * c + 1] = fmaf(wv.y, y0, upd0[4 * c + 1]);
      upd0[4 * c + 2] = fmaf(wv.z, y0, upd0[4 * c + 2]);
      upd0[4 * c + 3] = fmaf(wv.w, y0, upd0[4 * c + 3]);
      upd1[4 * c    ] = fmaf(wv.x, y1, upd1[4 * c    ]);
      upd1[4 * c + 1] = fmaf(wv.y, y1, upd1[4 * c + 1]);
      upd1[4 * c + 2] = fmaf(wv.z, y1, upd1[4 * c + 2]);
      upd1[4 * c + 3] = fmaf(wv.w, y1, upd1[4 * c + 3]);
    }
  }

  __syncthreads();                       // p_lds dead -> overlay becomes red
#pragma unroll
  for (int k = 0; k < CC; ++k) {
    RED(q, k, lane)      = upd0[k];
    RED(q, k, lane + 64) = upd1[k];
  }
  __syncthreads();

  const int c0 = q * 4;                  // this wave finalizes 4 channels
#pragma unroll
  for (int cc = 0; cc < 4; ++cc) {
    const int c = c0 + cc;
    const float bias = b2[c];
#pragma unroll
    for (int it = 0; it < 2; ++it) {
      const int px = lane + it * 64;
      float s = (RED(0, c, px) + RED(1, c, px)) +
                (RED(2, c, px) + RED(3, c, px)) + bias;
      const int ctr = ((px >> 4) + 1) * 18 + (px & 15) + 1;
      const int h = h0 + (px >> 4), w = w0 + (px & 15);
      rawout[b * CHW + c * HW + h * WW + w] = xt[c][ctr] + s * fire_lds[px];
    }
  }
#undef P_LDS
#undef RED
}

// ---------------- Final kernel: life mask + clip -> output -----------------
// grid 1152 = 8 batches x 144; block = 64 pixels x 4 channel quads.
__global__ __launch_bounds__(256) void ca_life(
    const float* __restrict__ prelife, const float* __restrict__ raw,
    float* __restrict__ xnext)
{
  const int lane = threadIdx.x & 63;
  const int g    = threadIdx.x >> 6;        // channel quad 0..3
  const int b    = blockIdx.x & 7;
  const int seg  = blockIdx.x >> 3;
  const int rem  = seg * 64 + lane;
  const int h = rem / WW;
  const int w = rem - h * WW;
  const int P = b * HW + rem;
  const bool hm = (h > 0), hp = (h < HH - 1), wm = (w > 0), wp = (w < WW - 1);

  float m2;
  {
    const float* xr = raw + b * CHW + 3 * HW + h * WW + w;
    m2 = xr[0];
    if (hm) {
      m2 = fmaxf(m2, xr[-WW]);
      if (wm) m2 = fmaxf(m2, xr[-WW - 1]);
      if (wp) m2 = fmaxf(m2, xr[-WW + 1]);
    }
    if (wm) m2 = fmaxf(m2, xr[-1]);
    if (wp) m2 = fmaxf(m2, xr[ 1]);
    if (hp) {
      m2 = fmaxf(m2, xr[WW]);
      if (wm) m2 = fmaxf(m2, xr[WW - 1]);
      if (wp) m2 = fmaxf(m2, xr[WW + 1]);
    }
  }
  const float life = ((prelife[P] > 0.1f) && (m2 > 0.1f)) ? 1.f : 0.f;

  const int base = b * CHW + h * WW + w;
#pragma unroll
  for (int cc = 0; cc < 4; ++cc) {
    const int c = g + cc * 4;               // wave-uniform
    float v = raw[base + c * HW] * life;
    v = fminf(fmaxf(v, -10.f), 10.f);
    xnext[base + c * HW] = v;
  }
}

// ---------------- launcher ----------------
extern "C" void kernel_launch(void* const* d_in, const int* in_sizes, int n_in,
                              void* d_out, int out_size, void* d_ws, size_t ws_size,
                              hipStream_t stream) {
  const float* x  = (const float*)d_in[0];
  const float* w1 = (const float*)d_in[1];
  const float* b1 = (const float*)d_in[2];
  const float* w2 = (const float*)d_in[3];
  const float* b2 = (const float*)d_in[4];
  float* out = (float*)d_out;

  char* ws = (char*)d_ws;
  const size_t BUF = (size_t)NPIX * CC * sizeof(float);   // 4,718,592 B
  float* rawA = (float*)(ws);
  float* rawB = (float*)(ws + BUF);
  float* w2t  = (float*)(ws + 2 * BUF);                   // 8 KiB
  float* plA  = (float*)(ws + 2 * BUF + 8192);            // NPIX floats
  float* plB  = (float*)(ws + 2 * BUF + 8192 + (size_t)NPIX * 4);

  hipLaunchKernelGGL(transp_w2, dim3(8), dim3(256), 0, stream, w2, w2t);

  for (int i = 0; i < STEPS; ++i) {
    uint32_t ka, kb;
    threefry2x32(0u, 42u, 0u, (uint32_t)i, ka, kb);       // fold_in(key(42), i)
    const float* src = (i == 0) ? x : ((i & 1) ? rawA : rawB);
    const float* plp = (i & 1) ? plA : plB;
    float* ro        = (i & 1) ? rawB : rawA;             // raw_i
    float* po        = (i & 1) ? plB : plA;               // prelife_i
    hipLaunchKernelGGL(ca_fused, dim3(8 * 72), dim3(256), 0, stream,
                       src, plp, w1, b1, w2t, b2, ro, po, ka, kb, (i == 0) ? 0 : 1);
  }
  // raw_15 / prelife_15 are in rawB / plB (15 is odd)
  hipLaunchKernelGGL(ca_life, dim3(NPIX / 64), dim3(256), 0, stream,
                     plB, rawB, out);
  (void)in_sizes; (void)n_in; (void)out_size; (void)ws_size;
}

// Round 10
// 415.905 us; speedup vs baseline: 1.3226x; 1.3226x over previous
//
#include <hip/hip_runtime.h>
#include <stdint.h>

#define BB 8
#define CC 16
#define HH 96
#define WW 96
#define HID 128
#define HW (HH*WW)            // 9216
#define CHW (CC*HW)           // 147456
#define NPIX (BB*HW)          // 73728
#define STEPS 16

// ---------------- Threefry-2x32 (JAX-compatible, 20 rounds) ----------------
__host__ __device__ inline void threefry2x32(uint32_t k0, uint32_t k1,
                                             uint32_t x0, uint32_t x1,
                                             uint32_t& o0, uint32_t& o1) {
  const uint32_t ks2 = k0 ^ k1 ^ 0x1BD11BDAu;
  uint32_t v0 = x0 + k0, v1 = x1 + k1;
#define RL(v, r) (((v) << (r)) | ((v) >> (32 - (r))))
#define RND(r) { v0 += v1; v1 = RL(v1, r); v1 ^= v0; }
  RND(13) RND(15) RND(26) RND(6)   v0 += k1;  v1 += ks2 + 1u;
  RND(17) RND(29) RND(16) RND(24)  v0 += ks2; v1 += k0 + 2u;
  RND(13) RND(15) RND(26) RND(6)   v0 += k0;  v1 += k1 + 3u;
  RND(17) RND(29) RND(16) RND(24)  v0 += k1;  v1 += ks2 + 4u;
  RND(13) RND(15) RND(26) RND(6)   v0 += ks2; v1 += k0 + 5u;
#undef RND
#undef RL
  o0 = v0; o1 = v1;
}

// fire: jax.random.uniform(key_i,(B,1,H,W)) < 0.5 ; partitionable threefry:
// bits[j] = x0 ^ x1 of threefry(key_i, (0, j)); u<0.5 <=> top bit clear.
__device__ inline float fire_val(uint32_t ka, uint32_t kb, uint32_t j) {
  uint32_t r0, r1;
  threefry2x32(ka, kb, 0u, j, r0, r1);
  return ((r0 ^ r1) & 0x80000000u) ? 0.0f : 1.0f;
}

// ---------------- w2 transpose: (16,128) -> (128,16) ----------------
__global__ void transp_w2(const float* __restrict__ w2, float* __restrict__ w2t) {
  int i = threadIdx.x + blockIdx.x * blockDim.x;
  if (i < CC * HID) {
    int o = i / HID, k = i - o * HID;
    w2t[k * CC + o] = w2[i];
  }
}

// ---------------- Fused step kernel -----------------------------------------
// Validated cost model (R5-R9): the MLP's LDS feature re-reads are BANDWIDTH
// bound (1.8 GB/step -> ~26us); weight streams must stay on the SCALAR pipe
// (LDS broadcast = 16B/slot, unhideable latency, R8: +15us); pinned feature
// arrays fit only at 1 px/lane (R8 pin held at VGPR=84; R9's 96 floats
// spilled). R10 = 1 px/lane + pins + s_load weights + no w1 LDS (25KB/block
// -> up to 6 blocks/CU). Grid 1152 = 8 batches x 144 tiles (XCD swizzle).
__global__ __launch_bounds__(256, 3) void ca_fused(
    const float* __restrict__ src,     // x0 (step 0) or raw_{i-1}
    const float* __restrict__ plprev,  // prelife_{i-1} (ignored when step 0)
    const float* __restrict__ w1,  const float* __restrict__ b1,
    const float* __restrict__ w2t, const float* __restrict__ b2,
    float* __restrict__ rawout, float* __restrict__ plout,
    uint32_t ka, uint32_t kb, int apply_life)
{
  __shared__ float xt[CC][100];      // x_i tile, 10x10 halo'd   6.4 KiB
  __shared__ float raw3[144];        // raw ch3, 12x12
  __shared__ float life_l[100];
  __shared__ float fire_lds[64];
  __shared__ float ovl[4 * CC * 64]; // overlay: p_lds(12K) / red(16K)
#define P_LDS(f, l) ovl[(f) * 64 + (l)]
#define RED(qq, k, l) ovl[(((qq) * CC) + (k)) * 64 + (l)]

  const int tid  = threadIdx.x;
  const int lane = tid & 63;
  const int q    = __builtin_amdgcn_readfirstlane(tid >> 6);  // wave-uniform
  const int b    = blockIdx.x & 7;           // batch == XCD slot
  const int t    = blockIdx.x >> 3;          // tile 0..143
  const int h0   = (t / 12) * 8, w0 = (t % 12) * 8;
  const int py   = lane >> 3, px = lane & 7; // interior pixel coords
  const int h    = h0 + py, w = w0 + px;
  const int P    = b * HW + h * WW + w;      // global pixel id

  if (q == 0) fire_lds[lane] = fire_val(ka, kb, (uint32_t)P);

  // ---- A1: raw ch3 12x12 (only needed when applying life)
  if (apply_life) {
    if (tid < 144) {
      const int r = tid / 12, c = tid - r * 12;
      const int hh = h0 - 2 + r, ww = w0 - 2 + c;
      float v = 0.f;
      if (hh >= 0 && hh < HH && ww >= 0 && ww < WW)
        v = src[b * CHW + 3 * HW + hh * WW + ww];
      raw3[tid] = v;
    }
    __syncthreads();
    // ---- A2: life on the 10x10 halo region
    if (tid < 100) {
      const int r = tid / 10, c = tid - r * 10;
      float m = raw3[r * 12 + c];
      m = fmaxf(m, raw3[r * 12 + c + 1]); m = fmaxf(m, raw3[r * 12 + c + 2]);
      m = fmaxf(m, raw3[(r + 1) * 12 + c]);     m = fmaxf(m, raw3[(r + 1) * 12 + c + 1]);
      m = fmaxf(m, raw3[(r + 1) * 12 + c + 2]); m = fmaxf(m, raw3[(r + 2) * 12 + c]);
      m = fmaxf(m, raw3[(r + 2) * 12 + c + 1]); m = fmaxf(m, raw3[(r + 2) * 12 + c + 2]);
      const int hh = h0 - 1 + r, ww = w0 - 1 + c;
      float pl = 0.f;
      if (hh >= 0 && hh < HH && ww >= 0 && ww < WW)
        pl = plprev[b * HW + hh * WW + ww];
      life_l[tid] = ((m > 0.1f) && (pl > 0.1f)) ? 1.f : 0.f;
    }
    __syncthreads();
  }

  // ---- A3: build x_i tile (10x10 x 16ch), zero outside image
  for (int i = tid; i < CC * 100; i += 256) {
    const int ch = i / 100, rc = i - ch * 100;
    const int r = rc / 10, c = rc - r * 10;
    const int hh = h0 - 1 + r, ww = w0 - 1 + c;
    float v = 0.f;
    if (hh >= 0 && hh < HH && ww >= 0 && ww < WW) {
      v = src[b * CHW + ch * HW + hh * WW + ww];
      if (apply_life) {
        v *= life_l[rc];
        v = fminf(fmaxf(v, -10.f), 10.f);
      }
    }
    xt[ch][rc] = v;
  }
  __syncthreads();

  // ---- A4 (wave 0): prelife_i = 3x3 max of x_i ch3, interior pixels
  if (q == 0) {
    const int ctr0 = py * 10 + px;
    float m = xt[3][ctr0];
    m = fmaxf(m, xt[3][ctr0 + 1]);  m = fmaxf(m, xt[3][ctr0 + 2]);
    m = fmaxf(m, xt[3][ctr0 + 10]); m = fmaxf(m, xt[3][ctr0 + 11]);
    m = fmaxf(m, xt[3][ctr0 + 12]); m = fmaxf(m, xt[3][ctr0 + 20]);
    m = fmaxf(m, xt[3][ctr0 + 21]); m = fmaxf(m, xt[3][ctr0 + 22]);
    plout[P] = m;
  }

  // ---- B: perception from LDS tile (wave q: channels q, q+4, q+8, q+12)
  const int ctr = (1 + py) * 10 + (1 + px);
#pragma unroll
  for (int cc = 0; cc < 4; ++cc) {
    const int c = q + cc * 4;                 // wave-uniform
    const float* xc = &xt[c][0];
    const float v00 = xc[ctr - 11], v01 = xc[ctr - 10], v02 = xc[ctr - 9];
    const float v10 = xc[ctr - 1],  v11 = xc[ctr],      v12 = xc[ctr + 1];
    const float v20 = xc[ctr + 9],  v21 = xc[ctr + 10], v22 = xc[ctr + 11];
    P_LDS(c, lane)          = v11;
    P_LDS(CC + c, lane)     = ((v02 - v00) + 2.f * (v12 - v10) + (v22 - v20)) * 0.125f;
    P_LDS(2 * CC + c, lane) = ((v20 - v00) + 2.f * (v21 - v01) + (v22 - v02)) * 0.125f;
  }
  __syncthreads();

  // ---- B2: features into registers, PINNED (defeats LDS rematerialization)
  float p[3 * CC];
#pragma unroll
  for (int f = 0; f < 3 * CC; ++f) p[f] = P_LDS(f, lane);
#pragma unroll
  for (int f = 0; f < 3 * CC; ++f) asm volatile("" : "+v"(p[f]));

  // ---- C: MLP, 32 hidden rows per wave; weights via s_load float4 (global)
  float upd[CC];
#pragma unroll
  for (int k = 0; k < CC; ++k) upd[k] = 0.f;

  const int row0 = q * 32;
#pragma unroll 2
  for (int o = 0; o < 32; ++o) {
    const int row = row0 + o;
    const float4* wr4 = reinterpret_cast<const float4*>(w1 + row * 48);
    float a0 = b1[row], a1 = 0.f, a2 = 0.f, a3 = 0.f;
#pragma unroll
    for (int c = 0; c < 12; ++c) {
      const float4 wv = wr4[c];            // wave-uniform -> s_load_dwordx4
      a0 = fmaf(wv.x, p[4 * c    ], a0);
      a1 = fmaf(wv.y, p[4 * c + 1], a1);
      a2 = fmaf(wv.z, p[4 * c + 2], a2);
      a3 = fmaf(wv.w, p[4 * c + 3], a3);
    }
    const float y = fmaxf((a0 + a1) + (a2 + a3), 0.f);  // relu
    const float4* w2r4 = reinterpret_cast<const float4*>(w2t + row * CC);
#pragma unroll
    for (int c = 0; c < 4; ++c) {
      const float4 wv = w2r4[c];           // wave-uniform -> s_load_dwordx4
      upd[4 * c    ] = fmaf(wv.x, y, upd[4 * c    ]);
      upd[4 * c + 1] = fmaf(wv.y, y, upd[4 * c + 1]);
      upd[4 * c + 2] = fmaf(wv.z, y, upd[4 * c + 2]);
      upd[4 * c + 3] = fmaf(wv.w, y, upd[4 * c + 3]);
    }
  }

  __syncthreads();                       // p_lds dead -> reuse overlay as red
#pragma unroll
  for (int k = 0; k < CC; ++k) RED(q, k, lane) = upd[k];
  __syncthreads();

  const float fire = fire_lds[lane];
  const int c0 = q * 4;                  // this wave finalizes 4 channels
#pragma unroll
  for (int cc = 0; cc < 4; ++cc) {
    const int c = c0 + cc;
    float s = (RED(0, c, lane) + RED(1, c, lane)) +
              (RED(2, c, lane) + RED(3, c, lane)) + b2[c];
    // center x value from LDS (runtime c ok for LDS, never for reg arrays)
    rawout[b * CHW + c * HW + h * WW + w] = xt[c][ctr] + s * fire;
  }
#undef P_LDS
#undef RED
}

// ---------------- Final kernel: life mask + clip -> output -----------------
// grid 1152 = 8 batches x 144; block = 64 pixels x 4 channel quads.
__global__ __launch_bounds__(256) void ca_life(
    const float* __restrict__ prelife, const float* __restrict__ raw,
    float* __restrict__ xnext)
{
  const int lane = threadIdx.x & 63;
  const int g    = threadIdx.x >> 6;        // channel quad 0..3
  const int b    = blockIdx.x & 7;
  const int seg  = blockIdx.x >> 3;
  const int rem  = seg * 64 + lane;
  const int h = rem / WW;
  const int w = rem - h * WW;
  const int P = b * HW + rem;
  const bool hm = (h > 0), hp = (h < HH - 1), wm = (w > 0), wp = (w < WW - 1);

  float m2;
  {
    const float* xr = raw + b * CHW + 3 * HW + h * WW + w;
    m2 = xr[0];
    if (hm) {
      m2 = fmaxf(m2, xr[-WW]);
      if (wm) m2 = fmaxf(m2, xr[-WW - 1]);
      if (wp) m2 = fmaxf(m2, xr[-WW + 1]);
    }
    if (wm) m2 = fmaxf(m2, xr[-1]);
    if (wp) m2 = fmaxf(m2, xr[ 1]);
    if (hp) {
      m2 = fmaxf(m2, xr[WW]);
      if (wm) m2 = fmaxf(m2, xr[WW - 1]);
      if (wp) m2 = fmaxf(m2, xr[WW + 1]);
    }
  }
  const float life = ((prelife[P] > 0.1f) && (m2 > 0.1f)) ? 1.f : 0.f;

  const int base = b * CHW + h * WW + w;
#pragma unroll
  for (int cc = 0; cc < 4; ++cc) {
    const int c = g + cc * 4;               // wave-uniform
    float v = raw[base + c * HW] * life;
    v = fminf(fmaxf(v, -10.f), 10.f);
    xnext[base + c * HW] = v;
  }
}

// ---------------- launcher ----------------
extern "C" void kernel_launch(void* const* d_in, const int* in_sizes, int n_in,
                              void* d_out, int out_size, void* d_ws, size_t ws_size,
                              hipStream_t stream) {
  const float* x  = (const float*)d_in[0];
  const float* w1 = (const float*)d_in[1];
  const float* b1 = (const float*)d_in[2];
  const float* w2 = (const float*)d_in[3];
  const float* b2 = (const float*)d_in[4];
  float* out = (float*)d_out;

  char* ws = (char*)d_ws;
  const size_t BUF = (size_t)NPIX * CC * sizeof(float);   // 4,718,592 B
  float* rawA = (float*)(ws);
  float* rawB = (float*)(ws + BUF);
  float* w2t  = (float*)(ws + 2 * BUF);                   // 8 KiB
  float* plA  = (float*)(ws + 2 * BUF + 8192);            // NPIX floats
  float* plB  = (float*)(ws + 2 * BUF + 8192 + (size_t)NPIX * 4);

  hipLaunchKernelGGL(transp_w2, dim3(8), dim3(256), 0, stream, w2, w2t);

  for (int i = 0; i < STEPS; ++i) {
    uint32_t ka, kb;
    threefry2x32(0u, 42u, 0u, (uint32_t)i, ka, kb);       // fold_in(key(42), i)
    const float* src = (i == 0) ? x : ((i & 1) ? rawA : rawB);
    const float* plp = (i & 1) ? plA : plB;
    float* ro        = (i & 1) ? rawB : rawA;             // raw_i
    float* po        = (i & 1) ? plB : plA;               // prelife_i
    hipLaunchKernelGGL(ca_fused, dim3(NPIX / 64), dim3(256), 0, stream,
                       src, plp, w1, b1, w2t, b2, ro, po, ka, kb, (i == 0) ? 0 : 1);
  }
  // raw_15 / prelife_15 are in rawB / plB (15 is odd)
  hipLaunchKernelGGL(ca_life, dim3(NPIX / 64), dim3(256), 0, stream,
                     plB, rawB, out);
  (void)in_sizes; (void)n_in; (void)out_size; (void)ws_size;
}